// Round 1
// baseline (3003.078 us; speedup 1.0000x reference)
//
#include <hip/hip_runtime.h>
#include <hip/hip_bf16.h>

typedef __attribute__((ext_vector_type(8))) short short8;
typedef __attribute__((ext_vector_type(4))) float floatx4;

#define NB 128      // batch N
#define LS 64       // seq L
#define HD 512      // hidden H
#define ED 512      // embed E
#define NH 65536    // NB*HD elements per s-slab
#define WST (64*NH) // elements per wavefront buffer slot
#define LDA 72      // LDS tile stride (64 + 8 pad, keeps 16B alignment)

// ws layout (byte offsets)
#define OFF_WIN    0ull         // W_in bf16   [512*512]
#define OFF_WSANI  524288ull    // W_sani bf16 [512*1024]
#define OFF_WOUT   1572864ull   // W_out bf16  [512*512]
#define OFF_XT     2097152ull   // x_t bf16    [64][128][512]
#define OFF_WBUF   10485760ull  // 3 rotating wavefront bufs bf16 [3][64][128][512]
#define OFF_OUTS   35651584ull  // outs bf16   [64][128][512]
#define OFF_PART   44040192ull  // partials f32 [128]
#define OFF_Y      OFF_WBUF     // Y f32 [8192][512] aliases dead wbuf after recurrence

static __device__ __forceinline__ unsigned short f2b(float f) {
  unsigned u = __float_as_uint(f);
  u += 0x7fffu + ((u >> 16) & 1u);   // round-to-nearest-even
  return (unsigned short)(u >> 16);
}

// ---- shared GEMM pieces: BM=64, BN=128, BK=64, 256 threads (4 waves, 2x2) ----

__device__ __forceinline__ void gemm_core24(const unsigned short* As, const unsigned short* Bs,
                                            floatx4 acc[2][4], int wm, int wn, int lane) {
  const int rb = lane & 15;
  const int kg = (lane >> 4) * 8;
#pragma unroll
  for (int kk = 0; kk < 64; kk += 32) {
    short8 a[2], b[4];
#pragma unroll
    for (int i = 0; i < 2; ++i)
      a[i] = *(const short8*)&As[(wm * 32 + i * 16 + rb) * LDA + kk + kg];
#pragma unroll
    for (int j = 0; j < 4; ++j)
      b[j] = *(const short8*)&Bs[(wn * 64 + j * 16 + rb) * LDA + kk + kg];
#pragma unroll
    for (int i = 0; i < 2; ++i)
#pragma unroll
      for (int j = 0; j < 4; ++j)
        acc[i][j] = __builtin_amdgcn_mfma_f32_16x16x32_bf16(a[i], b[j], acc[i][j], 0, 0, 0);
  }
}

// A tile: 64 rows x 64 cols, bf16 source with row stride 512
__device__ __forceinline__ void stageA_bf16(unsigned short* As, const unsigned short* src, int tid) {
  int r = tid >> 3, kc = (tid & 7) * 8;
#pragma unroll
  for (int p = 0; p < 2; ++p)
    *(uint4*)&As[(r + p * 32) * LDA + kc] = *(const uint4*)(src + (size_t)(r + p * 32) * 512 + kc);
}

// A tile via embedding gather (fp32 table -> bf16)
__device__ __forceinline__ void stageA_emb(unsigned short* As, const float* table,
                                           const int* labels, int m0, int k0, int tid) {
  int r = tid >> 3, kc = (tid & 7) * 8;
#pragma unroll
  for (int p = 0; p < 2; ++p) {
    int row = r + p * 32;
    const float* s = table + (size_t)labels[m0 + row] * ED + k0 + kc;
    floatx4 f0 = *(const floatx4*)s;
    floatx4 f1 = *(const floatx4*)(s + 4);
    uint4 u;
    u.x = (unsigned)f2b(f0.x) | ((unsigned)f2b(f0.y) << 16);
    u.y = (unsigned)f2b(f0.z) | ((unsigned)f2b(f0.w) << 16);
    u.z = (unsigned)f2b(f1.x) | ((unsigned)f2b(f1.y) << 16);
    u.w = (unsigned)f2b(f1.z) | ((unsigned)f2b(f1.w) << 16);
    *(uint4*)&As[row * LDA + kc] = u;
  }
}

// B tile: 128 rows (of B^T) x 64 cols, bf16, row stride ldB
__device__ __forceinline__ void stageB(unsigned short* Bs, const unsigned short* src, int ldB, int tid) {
  int r = tid >> 3, kc = (tid & 7) * 8;
#pragma unroll
  for (int p = 0; p < 4; ++p)
    *(uint4*)&Bs[(r + p * 32) * LDA + kc] = *(const uint4*)(src + (size_t)(r + p * 32) * ldB + kc);
}

// ---- phase 1: x_t[l][n][h] = bf16( emb(labels) @ W_in^T + b_in ) ----
__global__ __launch_bounds__(256) void k_gemm_emb(const float* __restrict__ table,
                                                  const int* __restrict__ labels,
                                                  const unsigned short* __restrict__ Wb,
                                                  const float* __restrict__ bias,
                                                  unsigned short* __restrict__ xt) {
  __shared__ unsigned short As[64 * LDA];
  __shared__ unsigned short Bs[128 * LDA];
  int tid = threadIdx.x;
  int mtile = blockIdx.x >> 2, ntile = blockIdx.x & 3;
  int m0 = mtile * 64, n0 = ntile * 128;
  int lane = tid & 63, wave = tid >> 6, wm = wave >> 1, wn = wave & 1;
  floatx4 acc[2][4] = {};
  for (int k0 = 0; k0 < 512; k0 += 64) {
    stageA_emb(As, table, labels, m0, k0, tid);
    stageB(Bs, Wb + (size_t)n0 * 512 + k0, 512, tid);
    __syncthreads();
    gemm_core24(As, Bs, acc, wm, wn, lane);
    __syncthreads();
  }
  int rb = lane & 15, rg = (lane >> 4) * 4;
#pragma unroll
  for (int i = 0; i < 2; ++i)
#pragma unroll
    for (int j = 0; j < 4; ++j) {
      int col = n0 + wn * 64 + j * 16 + rb;
      float bv = bias[col];
#pragma unroll
      for (int reg = 0; reg < 4; ++reg) {
        int m = m0 + wm * 32 + i * 16 + rg + reg;
        int n = m >> 6, l = m & 63;
        xt[((size_t)l * NB + n) * HD + col] = f2b(acc[i][j][reg] + bv);
      }
    }
}

// ---- phase 2: one wavefront cell  h(s,li) = diag@W1^T + own@W2^T + b ----
__global__ __launch_bounds__(256) void k_gemm_cell(const unsigned short* __restrict__ xt,
                                                   unsigned short* __restrict__ wbuf,
                                                   unsigned short* __restrict__ outs,
                                                   const unsigned short* __restrict__ Wsani,
                                                   const float* __restrict__ bias,
                                                   int t, int s_min) {
  __shared__ unsigned short As[64 * LDA];
  __shared__ unsigned short Bs[128 * LDA];
  int tid = threadIdx.x;
  int cell = blockIdx.x >> 3, sub = blockIdx.x & 7;
  int mtile = sub >> 2, ntile = sub & 3;
  int m0 = mtile * 64, n0 = ntile * 128;
  int s = s_min + cell, li = t - s;
  const unsigned short* own  = (li == 1) ? xt + (size_t)s * NH
                                         : wbuf + (size_t)((t + 2) % 3) * WST + (size_t)s * NH;
  const unsigned short* diag = (li == 1) ? xt + (size_t)(s - 1) * NH
                                         : wbuf + (size_t)((t + 1) % 3) * WST + (size_t)(s - 1) * NH;
  unsigned short* dst = wbuf + (size_t)(t % 3) * WST + (size_t)s * NH;
  int lane = tid & 63, wave = tid >> 6, wm = wave >> 1, wn = wave & 1;
  floatx4 acc[2][4] = {};
  for (int k0 = 0; k0 < 1024; k0 += 64) {
    // k < 512: states part (diag) x W_sani[:, :512]; k >= 512: h part (own) x W_sani[:, 512:]
    const unsigned short* asrc = (k0 < 512) ? (diag + (size_t)m0 * 512 + k0)
                                            : (own + (size_t)m0 * 512 + (k0 - 512));
    stageA_bf16(As, asrc, tid);
    stageB(Bs, Wsani + (size_t)n0 * 1024 + k0, 1024, tid);
    __syncthreads();
    gemm_core24(As, Bs, acc, wm, wn, lane);
    __syncthreads();
  }
  int rb = lane & 15, rg = (lane >> 4) * 4;
  bool isout = (li == s);
  unsigned short* dst2 = outs + (size_t)s * NH;
#pragma unroll
  for (int i = 0; i < 2; ++i)
#pragma unroll
    for (int j = 0; j < 4; ++j) {
      int col = n0 + wn * 64 + j * 16 + rb;
      float bv = bias[col];
#pragma unroll
      for (int reg = 0; reg < 4; ++reg) {
        int row = m0 + wm * 32 + i * 16 + rg + reg;
        unsigned short v = f2b(acc[i][j][reg] + bv);
        dst[(size_t)row * HD + col] = v;
        if (isout) dst2[(size_t)row * HD + col] = v;
      }
    }
}

// ---- phase 3: Y = outs_flat @ W_out^T + b_out  (fp32 out) ----
__global__ __launch_bounds__(256) void k_gemm_out(const unsigned short* __restrict__ outs,
                                                  const unsigned short* __restrict__ Wb,
                                                  const float* __restrict__ bias,
                                                  float* __restrict__ Y) {
  __shared__ unsigned short As[64 * LDA];
  __shared__ unsigned short Bs[128 * LDA];
  int tid = threadIdx.x;
  int mtile = blockIdx.x >> 2, ntile = blockIdx.x & 3;
  int m0 = mtile * 64, n0 = ntile * 128;
  int lane = tid & 63, wave = tid >> 6, wm = wave >> 1, wn = wave & 1;
  floatx4 acc[2][4] = {};
  for (int k0 = 0; k0 < 512; k0 += 64) {
    stageA_bf16(As, outs + (size_t)m0 * 512 + k0, tid);
    stageB(Bs, Wb + (size_t)n0 * 512 + k0, 512, tid);
    __syncthreads();
    gemm_core24(As, Bs, acc, wm, wn, lane);
    __syncthreads();
  }
  int rb = lane & 15, rg = (lane >> 4) * 4;
#pragma unroll
  for (int i = 0; i < 2; ++i)
#pragma unroll
    for (int j = 0; j < 4; ++j) {
      int col = n0 + wn * 64 + j * 16 + rb;
      float bv = bias[col];
#pragma unroll
      for (int reg = 0; reg < 4; ++reg) {
        int row = m0 + wm * 32 + i * 16 + rg + reg;
        Y[(size_t)row * 512 + col] = acc[i][j][reg] + bv;
      }
    }
}

// ---- weights fp32 -> bf16 (one float4 per thread over concat regions) ----
__global__ __launch_bounds__(256) void k_cvtw(const float* __restrict__ Win,
                                              const float* __restrict__ Wsani,
                                              const float* __restrict__ Wout,
                                              unsigned short* __restrict__ dWin,
                                              unsigned short* __restrict__ dWsani,
                                              unsigned short* __restrict__ dWout) {
  int i = blockIdx.x * 256 + threadIdx.x;  // float4 index, total 262144
  const float* src;
  unsigned short* dst;
  int off;
  if (i < 65536)       { src = Win;   dst = dWin;   off = i; }
  else if (i < 196608) { src = Wsani; dst = dWsani; off = i - 65536; }
  else                 { src = Wout;  dst = dWout;  off = i - 196608; }
  floatx4 v = *(const floatx4*)(src + (size_t)off * 4);
  uint2 u;
  u.x = (unsigned)f2b(v.x) | ((unsigned)f2b(v.y) << 16);
  u.y = (unsigned)f2b(v.z) | ((unsigned)f2b(v.w) << 16);
  *(uint2*)(dst + (size_t)off * 4) = u;
}

__global__ void k_copy(const uint4* __restrict__ src, uint4* __restrict__ dst, int n) {
  int i = blockIdx.x * 256 + threadIdx.x;
  if (i < n) dst[i] = src[i];
}

// ---- loss: per n, column-softmax over 64 consecutive Y rows, dot with emb ----
__global__ __launch_bounds__(256) void k_loss(const float* __restrict__ Y,
                                              const float* __restrict__ table,
                                              const int* __restrict__ labels,
                                              float* __restrict__ partials) {
  int n = blockIdx.x, tid = threadIdx.x;
  float total = 0.f;
#pragma unroll
  for (int e2 = 0; e2 < 2; ++e2) {
    int e = e2 * 256 + tid;
    float mx = -1e30f;
    for (int l = 0; l < 64; ++l)
      mx = fmaxf(mx, Y[(size_t)(n * 64 + l) * 512 + e]);
    float se = 0.f;
    for (int l = 0; l < 64; ++l)
      se += expf(Y[(size_t)(n * 64 + l) * 512 + e] - mx);
    float lse = mx + logf(se);
    for (int l = 0; l < 64; ++l) {
      float embv = table[(size_t)labels[n * 64 + l] * ED + e];
      total += embv * (Y[(size_t)(n * 64 + l) * 512 + e] - lse);
    }
  }
  __shared__ float red[256];
  red[tid] = total;
  __syncthreads();
  for (int s2 = 128; s2 > 0; s2 >>= 1) {
    if (tid < s2) red[tid] += red[tid + s2];
    __syncthreads();
  }
  if (tid == 0) partials[n] = red[0];
}

__global__ void k_final(const float* __restrict__ partials, float* __restrict__ out) {
  if (threadIdx.x == 0) {
    double s = 0.0;
    for (int i = 0; i < 128; ++i) s += (double)partials[i];
    out[0] = (float)(-s / 65536.0);
  }
}

extern "C" void kernel_launch(void* const* d_in, const int* in_sizes, int n_in,
                              void* d_out, int out_size, void* d_ws, size_t ws_size,
                              hipStream_t stream) {
  const int*   labels = (const int*)d_in[0];
  const float* table  = (const float*)d_in[1];
  const float* W_in   = (const float*)d_in[2];
  const float* b_in   = (const float*)d_in[3];
  const float* W_sani = (const float*)d_in[4];
  const float* b_sani = (const float*)d_in[5];
  const float* W_out  = (const float*)d_in[6];
  const float* b_out  = (const float*)d_in[7];

  char* ws = (char*)d_ws;
  unsigned short* Win_b   = (unsigned short*)(ws + OFF_WIN);
  unsigned short* Wsani_b = (unsigned short*)(ws + OFF_WSANI);
  unsigned short* Wout_b  = (unsigned short*)(ws + OFF_WOUT);
  unsigned short* xt      = (unsigned short*)(ws + OFF_XT);
  unsigned short* wbuf    = (unsigned short*)(ws + OFF_WBUF);
  unsigned short* outs    = (unsigned short*)(ws + OFF_OUTS);
  float*          parts   = (float*)(ws + OFF_PART);
  float*          Y       = (float*)(ws + OFF_Y);

  k_cvtw<<<1024, 256, 0, stream>>>(W_in, W_sani, W_out, Win_b, Wsani_b, Wout_b);
  k_gemm_emb<<<512, 256, 0, stream>>>(table, labels, Win_b, b_in, xt);
  k_copy<<<32, 256, 0, stream>>>((const uint4*)xt, (uint4*)outs, 8192);  // outs[0] = x_t[0]

  for (int t = 2; t <= 126; ++t) {
    int s_min = (t + 1) >> 1;          // ceil(t/2), >= 1 for t >= 2
    int s_max = (t - 1 < 63) ? t - 1 : 63;
    int cells = s_max - s_min + 1;
    k_gemm_cell<<<cells * 8, 256, 0, stream>>>(xt, wbuf, outs, Wsani_b, b_sani, t, s_min);
  }

  k_gemm_out<<<512, 256, 0, stream>>>(outs, Wout_b, b_out, Y);
  k_loss<<<128, 256, 0, stream>>>(Y, table, labels, parts);
  k_final<<<1, 64, 0, stream>>>(parts, (float*)d_out);
}

// Round 2
// 1838.566 us; speedup vs baseline: 1.6334x; 1.6334x over previous
//
#include <hip/hip_runtime.h>
#include <hip/hip_bf16.h>

typedef __attribute__((ext_vector_type(8))) short short8;
typedef __attribute__((ext_vector_type(4))) float floatx4;

#define NB 128      // batch N
#define LS 64       // seq L
#define HD 512      // hidden H
#define ED 512      // embed E
#define NH 65536    // NB*HD elements per s-slab
#define LDA 72      // LDS tile stride (64 + 8 pad, keeps 16B alignment)

// ws layout (byte offsets)
#define OFF_WIN    0ull          // W_in bf16   [512*512]
#define OFF_WSANI  524288ull     // W_sani bf16 [512*1024]
#define OFF_WOUT   1572864ull    // W_out bf16  [512*512]
#define OFF_XT     2097152ull    // x_t bf16    [64][128][512]   (= level 0)
#define OFF_LVL0   10485760ull   // level ping  bf16 [64][128][512]
#define OFF_LVL1   18874368ull   // level pong  bf16 [64][128][512]
#define OFF_OUTS   27262976ull   // outs bf16   [64][128][512]
#define OFF_PART   35651584ull   // partials f32 [128]
#define OFF_Y      OFF_LVL0      // Y f32 [8192][512] aliases dead lvl bufs after recurrence

static __device__ __forceinline__ unsigned short f2b(float f) {
  unsigned u = __float_as_uint(f);
  u += 0x7fffu + ((u >> 16) & 1u);   // round-to-nearest-even
  return (unsigned short)(u >> 16);
}

// ---- shared GEMM pieces: BM=64, BN=128, BK=64, 256 threads (4 waves, 2x2) ----

__device__ __forceinline__ void gemm_core24(const unsigned short* As, const unsigned short* Bs,
                                            floatx4 acc[2][4], int wm, int wn, int lane) {
  const int rb = lane & 15;
  const int kg = (lane >> 4) * 8;
#pragma unroll
  for (int kk = 0; kk < 64; kk += 32) {
    short8 a[2], b[4];
#pragma unroll
    for (int i = 0; i < 2; ++i)
      a[i] = *(const short8*)&As[(wm * 32 + i * 16 + rb) * LDA + kk + kg];
#pragma unroll
    for (int j = 0; j < 4; ++j)
      b[j] = *(const short8*)&Bs[(wn * 64 + j * 16 + rb) * LDA + kk + kg];
#pragma unroll
    for (int i = 0; i < 2; ++i)
#pragma unroll
      for (int j = 0; j < 4; ++j)
        acc[i][j] = __builtin_amdgcn_mfma_f32_16x16x32_bf16(a[i], b[j], acc[i][j], 0, 0, 0);
  }
}

// A tile: 64 rows x 64 cols, bf16 source with row stride 512
__device__ __forceinline__ void stageA_bf16(unsigned short* As, const unsigned short* src, int tid) {
  int r = tid >> 3, kc = (tid & 7) * 8;
#pragma unroll
  for (int p = 0; p < 2; ++p)
    *(uint4*)&As[(r + p * 32) * LDA + kc] = *(const uint4*)(src + (size_t)(r + p * 32) * 512 + kc);
}

// A tile via embedding gather (fp32 table -> bf16)
__device__ __forceinline__ void stageA_emb(unsigned short* As, const float* table,
                                           const int* labels, int m0, int k0, int tid) {
  int r = tid >> 3, kc = (tid & 7) * 8;
#pragma unroll
  for (int p = 0; p < 2; ++p) {
    int row = r + p * 32;
    const float* s = table + (size_t)labels[m0 + row] * ED + k0 + kc;
    floatx4 f0 = *(const floatx4*)s;
    floatx4 f1 = *(const floatx4*)(s + 4);
    uint4 u;
    u.x = (unsigned)f2b(f0.x) | ((unsigned)f2b(f0.y) << 16);
    u.y = (unsigned)f2b(f0.z) | ((unsigned)f2b(f0.w) << 16);
    u.z = (unsigned)f2b(f1.x) | ((unsigned)f2b(f1.y) << 16);
    u.w = (unsigned)f2b(f1.z) | ((unsigned)f2b(f1.w) << 16);
    *(uint4*)&As[row * LDA + kc] = u;
  }
}

// B tile: 128 rows (of B^T) x 64 cols, bf16, row stride ldB
__device__ __forceinline__ void stageB(unsigned short* Bs, const unsigned short* src, int ldB, int tid) {
  int r = tid >> 3, kc = (tid & 7) * 8;
#pragma unroll
  for (int p = 0; p < 4; ++p)
    *(uint4*)&Bs[(r + p * 32) * LDA + kc] = *(const uint4*)(src + (size_t)(r + p * 32) * ldB + kc);
}

// ---- phase 1: x_t[l][n][h] = bf16( emb(labels) @ W_in^T + b_in ) ----
__global__ __launch_bounds__(256) void k_gemm_emb(const float* __restrict__ table,
                                                  const int* __restrict__ labels,
                                                  const unsigned short* __restrict__ Wb,
                                                  const float* __restrict__ bias,
                                                  unsigned short* __restrict__ xt) {
  __shared__ unsigned short As[64 * LDA];
  __shared__ unsigned short Bs[128 * LDA];
  int tid = threadIdx.x;
  int mtile = blockIdx.x >> 2, ntile = blockIdx.x & 3;
  int m0 = mtile * 64, n0 = ntile * 128;
  int lane = tid & 63, wave = tid >> 6, wm = wave >> 1, wn = wave & 1;
  floatx4 acc[2][4] = {};
  for (int k0 = 0; k0 < 512; k0 += 64) {
    stageA_emb(As, table, labels, m0, k0, tid);
    stageB(Bs, Wb + (size_t)n0 * 512 + k0, 512, tid);
    __syncthreads();
    gemm_core24(As, Bs, acc, wm, wn, lane);
    __syncthreads();
  }
  int rb = lane & 15, rg = (lane >> 4) * 4;
#pragma unroll
  for (int i = 0; i < 2; ++i)
#pragma unroll
    for (int j = 0; j < 4; ++j) {
      int col = n0 + wn * 64 + j * 16 + rb;
      float bv = bias[col];
#pragma unroll
      for (int reg = 0; reg < 4; ++reg) {
        int m = m0 + wm * 32 + i * 16 + rg + reg;
        int n = m >> 6, l = m & 63;
        xt[((size_t)l * NB + n) * HD + col] = f2b(acc[i][j][reg] + bv);
      }
    }
}

// ---- phase 2: one LEVEL  h(s,li) = h(s-1,li-1)@W1^T + h(s,li-1)@W2^T + b,
//      for all s in [li, 63] at once. src = level li-1 buffer, dst = level li. ----
__global__ __launch_bounds__(256) void k_gemm_level(const unsigned short* __restrict__ src,
                                                    unsigned short* __restrict__ dst,
                                                    unsigned short* __restrict__ outs,
                                                    const unsigned short* __restrict__ Wsani,
                                                    const float* __restrict__ bias,
                                                    int li) {
  __shared__ unsigned short As[64 * LDA];
  __shared__ unsigned short Bs[128 * LDA];
  int tid = threadIdx.x;
  int mtile = blockIdx.x >> 2, ntile = blockIdx.x & 3;
  int m0 = mtile * 64, n0 = ntile * 128;
  int s = li + (m0 >> 7);          // each 64-row A tile lies within one s-slab
  int nb0 = m0 & 127;              // row offset within the slab (0 or 64)
  const unsigned short* own  = src + (size_t)s * NH + (size_t)nb0 * HD;        // h(s, li-1)
  const unsigned short* diag = src + (size_t)(s - 1) * NH + (size_t)nb0 * HD;  // h(s-1, li-1)
  unsigned short* d = dst + (size_t)s * NH + (size_t)nb0 * HD;
  int lane = tid & 63, wave = tid >> 6, wm = wave >> 1, wn = wave & 1;
  floatx4 acc[2][4] = {};
  for (int k0 = 0; k0 < 1024; k0 += 64) {
    // k < 512: states part (diag) x W_sani[:, :512]; k >= 512: h part (own) x W_sani[:, 512:]
    const unsigned short* asrc = (k0 < 512) ? (diag + k0) : (own + (k0 - 512));
    stageA_bf16(As, asrc, tid);
    stageB(Bs, Wsani + (size_t)n0 * 1024 + k0, 1024, tid);
    __syncthreads();
    gemm_core24(As, Bs, acc, wm, wn, lane);
    __syncthreads();
  }
  int rb = lane & 15, rg = (lane >> 4) * 4;
  bool isout = (s == li);          // outs[li] = h(li, li)
  unsigned short* d2 = outs + (size_t)li * NH + (size_t)nb0 * HD;
#pragma unroll
  for (int i = 0; i < 2; ++i)
#pragma unroll
    for (int j = 0; j < 4; ++j) {
      int col = n0 + wn * 64 + j * 16 + rb;
      float bv = bias[col];
#pragma unroll
      for (int reg = 0; reg < 4; ++reg) {
        int row = wm * 32 + i * 16 + rg + reg;   // local row within tile
        unsigned short v = f2b(acc[i][j][reg] + bv);
        d[(size_t)row * HD + col] = v;
        if (isout) d2[(size_t)row * HD + col] = v;
      }
    }
}

// ---- phase 3: Y = outs_flat @ W_out^T + b_out  (fp32 out) ----
__global__ __launch_bounds__(256) void k_gemm_out(const unsigned short* __restrict__ outs,
                                                  const unsigned short* __restrict__ Wb,
                                                  const float* __restrict__ bias,
                                                  float* __restrict__ Y) {
  __shared__ unsigned short As[64 * LDA];
  __shared__ unsigned short Bs[128 * LDA];
  int tid = threadIdx.x;
  int mtile = blockIdx.x >> 2, ntile = blockIdx.x & 3;
  int m0 = mtile * 64, n0 = ntile * 128;
  int lane = tid & 63, wave = tid >> 6, wm = wave >> 1, wn = wave & 1;
  floatx4 acc[2][4] = {};
  for (int k0 = 0; k0 < 512; k0 += 64) {
    stageA_bf16(As, outs + (size_t)m0 * 512 + k0, tid);
    stageB(Bs, Wb + (size_t)n0 * 512 + k0, 512, tid);
    __syncthreads();
    gemm_core24(As, Bs, acc, wm, wn, lane);
    __syncthreads();
  }
  int rb = lane & 15, rg = (lane >> 4) * 4;
#pragma unroll
  for (int i = 0; i < 2; ++i)
#pragma unroll
    for (int j = 0; j < 4; ++j) {
      int col = n0 + wn * 64 + j * 16 + rb;
      float bv = bias[col];
#pragma unroll
      for (int reg = 0; reg < 4; ++reg) {
        int row = m0 + wm * 32 + i * 16 + rg + reg;
        Y[(size_t)row * 512 + col] = acc[i][j][reg] + bv;
      }
    }
}

// ---- weights fp32 -> bf16 (one float4 per thread over concat regions) ----
__global__ __launch_bounds__(256) void k_cvtw(const float* __restrict__ Win,
                                              const float* __restrict__ Wsani,
                                              const float* __restrict__ Wout,
                                              unsigned short* __restrict__ dWin,
                                              unsigned short* __restrict__ dWsani,
                                              unsigned short* __restrict__ dWout) {
  int i = blockIdx.x * 256 + threadIdx.x;  // float4 index, total 262144
  const float* src;
  unsigned short* dst;
  int off;
  if (i < 65536)       { src = Win;   dst = dWin;   off = i; }
  else if (i < 196608) { src = Wsani; dst = dWsani; off = i - 65536; }
  else                 { src = Wout;  dst = dWout;  off = i - 196608; }
  floatx4 v = *(const floatx4*)(src + (size_t)off * 4);
  uint2 u;
  u.x = (unsigned)f2b(v.x) | ((unsigned)f2b(v.y) << 16);
  u.y = (unsigned)f2b(v.z) | ((unsigned)f2b(v.w) << 16);
  *(uint2*)(dst + (size_t)off * 4) = u;
}

__global__ void k_copy(const uint4* __restrict__ src, uint4* __restrict__ dst, int n) {
  int i = blockIdx.x * 256 + threadIdx.x;
  if (i < n) dst[i] = src[i];
}

// ---- loss: per n, column-softmax over 64 consecutive Y rows, dot with emb ----
__global__ __launch_bounds__(256) void k_loss(const float* __restrict__ Y,
                                              const float* __restrict__ table,
                                              const int* __restrict__ labels,
                                              float* __restrict__ partials) {
  int n = blockIdx.x, tid = threadIdx.x;
  float total = 0.f;
#pragma unroll
  for (int e2 = 0; e2 < 2; ++e2) {
    int e = e2 * 256 + tid;
    float mx = -1e30f;
    for (int l = 0; l < 64; ++l)
      mx = fmaxf(mx, Y[(size_t)(n * 64 + l) * 512 + e]);
    float se = 0.f;
    for (int l = 0; l < 64; ++l)
      se += expf(Y[(size_t)(n * 64 + l) * 512 + e] - mx);
    float lse = mx + logf(se);
    for (int l = 0; l < 64; ++l) {
      float embv = table[(size_t)labels[n * 64 + l] * ED + e];
      total += embv * (Y[(size_t)(n * 64 + l) * 512 + e] - lse);
    }
  }
  __shared__ float red[256];
  red[tid] = total;
  __syncthreads();
  for (int s2 = 128; s2 > 0; s2 >>= 1) {
    if (tid < s2) red[tid] += red[tid + s2];
    __syncthreads();
  }
  if (tid == 0) partials[n] = red[0];
}

__global__ void k_final(const float* __restrict__ partials, float* __restrict__ out) {
  if (threadIdx.x == 0) {
    double s = 0.0;
    for (int i = 0; i < 128; ++i) s += (double)partials[i];
    out[0] = (float)(-s / 65536.0);
  }
}

extern "C" void kernel_launch(void* const* d_in, const int* in_sizes, int n_in,
                              void* d_out, int out_size, void* d_ws, size_t ws_size,
                              hipStream_t stream) {
  const int*   labels = (const int*)d_in[0];
  const float* table  = (const float*)d_in[1];
  const float* W_in   = (const float*)d_in[2];
  const float* b_in   = (const float*)d_in[3];
  const float* W_sani = (const float*)d_in[4];
  const float* b_sani = (const float*)d_in[5];
  const float* W_out  = (const float*)d_in[6];
  const float* b_out  = (const float*)d_in[7];

  char* ws = (char*)d_ws;
  unsigned short* Win_b   = (unsigned short*)(ws + OFF_WIN);
  unsigned short* Wsani_b = (unsigned short*)(ws + OFF_WSANI);
  unsigned short* Wout_b  = (unsigned short*)(ws + OFF_WOUT);
  unsigned short* xt      = (unsigned short*)(ws + OFF_XT);
  unsigned short* lvl0    = (unsigned short*)(ws + OFF_LVL0);
  unsigned short* lvl1    = (unsigned short*)(ws + OFF_LVL1);
  unsigned short* outs    = (unsigned short*)(ws + OFF_OUTS);
  float*          parts   = (float*)(ws + OFF_PART);
  float*          Y       = (float*)(ws + OFF_Y);

  k_cvtw<<<1024, 256, 0, stream>>>(W_in, W_sani, W_out, Win_b, Wsani_b, Wout_b);
  k_gemm_emb<<<512, 256, 0, stream>>>(table, labels, Win_b, b_in, xt);
  k_copy<<<32, 256, 0, stream>>>((const uint4*)xt, (uint4*)outs, 8192);  // outs[0] = x_t[0]

  const unsigned short* srcp = xt;   // level 0 = x_t
  for (int li = 1; li <= 63; ++li) {
    unsigned short* dstp = (li & 1) ? lvl1 : lvl0;
    k_gemm_level<<<8 * (64 - li), 256, 0, stream>>>(srcp, dstp, outs, Wsani_b, b_sani, li);
    srcp = dstp;
  }

  k_gemm_out<<<512, 256, 0, stream>>>(outs, Wout_b, b_out, Y);
  k_loss<<<128, 256, 0, stream>>>(Y, table, labels, parts);
  k_final<<<1, 64, 0, stream>>>(parts, (float*)d_out);
}